// Round 3
// baseline (21.584 us; speedup 1.0000x reference)
//
#include <hip/hip_runtime.h>
#include <math.h>

#define BB 2048
#define NN 8192
#define HH 10
#define BETA 0.1f
#define CHUNK 2048   // elements per (row, split) block = 256 threads * 8
#define NSPLIT 4

// Hardware transcendentals: v_log_f32 = log2(x), v_exp_f32 = 2^x (~1 ulp each).
// Valid: x = yn - y[k] > 0 for active k (y strictly increasing cumsum of positives).
__device__ __forceinline__ float fast_log2(float x) {
    float r; asm("v_log_f32 %0, %1" : "=v"(r) : "v"(x)); return r;
}
__device__ __forceinline__ float fast_exp2(float x) {
    float r; asm("v_exp_f32 %0, %1" : "=v"(r) : "v"(x)); return r;
}

__device__ __forceinline__ float alpha_of(float yp,
    const float* __restrict__ aw1, const float* __restrict__ ab1,
    const float* __restrict__ aw2, const float* __restrict__ ab2) {
    float m = ab2[0];
    #pragma unroll
    for (int h = 0; h < HH; ++h)
        m += fmaxf(fmaf(yp, aw1[h], ab1[h]), 0.f) * aw2[h];
    const float g   = 1.f - expf(-BETA * yp);
    const float sig = 1.f / (1.f + expf(-m));
    return 1.f - sig * g;
}

// Kernel 1: per (row b, split s) partial sums over k in [s*CHUNK, s*CHUNK+CHUNK) ∩ range.
__global__ __launch_bounds__(256) void frac_partial_kernel(
    const float* __restrict__ y_plus,
    const int*   __restrict__ iidx,
    const float* __restrict__ DU,
    const float* __restrict__ Y,
    const float* __restrict__ aw1, const float* __restrict__ ab1,
    const float* __restrict__ aw2, const float* __restrict__ ab2,
    double2* __restrict__ ws2)
{
    const int b   = blockIdx.x;
    const int s   = blockIdx.y;
    const int tid = threadIdx.x;
    const int n   = iidx[b];

    const float a = alpha_of(y_plus[b], aw1, ab1, aw2, ab2);
    const float t = 1.f - a;

    const float* yr = Y  + (size_t)b * NN;
    const float* dr = DU + (size_t)b * NN;

    const bool need_main = (a != 0.f) && (a != 1.f) && (n >= 2);
    const bool need_trap = (a == 0.f) && (n >= 1);

    float sm = 0.f;   // main partial (this thread)
    float tr = 0.f;   // trapezoid partial

    if (need_main) {
        const int kend = n - 2;                       // inclusive
        const int k0 = s * CHUNK + tid * 8;
        if (k0 <= kend) {
            float4 ya = *reinterpret_cast<const float4*>(yr + k0);
            float4 yb = *reinterpret_cast<const float4*>(yr + k0 + 4);
            float4 da = *reinterpret_cast<const float4*>(dr + k0);
            float4 db = *reinterpret_cast<const float4*>(dr + k0 + 4);
            float ynext = (k0 + 8 <= kend + 1) ? yr[k0 + 8] : yb.w;  // <= n-1 <= 8191
            const float yn = yr[n];
            float yv[9] = {ya.x, ya.y, ya.z, ya.w, yb.x, yb.y, yb.z, yb.w, ynext};
            float dv[8] = {da.x, da.y, da.z, da.w, db.x, db.y, db.z, db.w};
            float p[9];
            #pragma unroll
            for (int j = 0; j < 9; ++j) {
                float x = fmaxf(yn - yv[j], 1e-30f);
                p[j] = fast_exp2(t * fast_log2(x));
            }
            #pragma unroll
            for (int q = 0; q < 8; ++q)
                if (k0 + q <= kend)
                    sm = fmaf(p[q] - p[q + 1], dv[q], sm);
        }
    }
    if (need_trap) {
        const int kend = n - 1;                       // inclusive segment index
        const int k0 = s * CHUNK + tid * 8;
        if (k0 <= kend) {
            float4 ya = *reinterpret_cast<const float4*>(yr + k0);
            float4 yb = *reinterpret_cast<const float4*>(yr + k0 + 4);
            float4 da = *reinterpret_cast<const float4*>(dr + k0);
            float4 db = *reinterpret_cast<const float4*>(dr + k0 + 4);
            float ynext = (k0 + 8 <= kend + 1) ? yr[k0 + 8] : yb.w;  // <= n <= 8191
            float dnext = (k0 + 8 <= kend + 1) ? dr[k0 + 8] : db.w;
            float yv[9] = {ya.x, ya.y, ya.z, ya.w, yb.x, yb.y, yb.z, yb.w, ynext};
            float dv[9] = {da.x, da.y, da.z, da.w, db.x, db.y, db.z, db.w, dnext};
            #pragma unroll
            for (int q = 0; q < 8; ++q)
                if (k0 + q <= kend)
                    tr += (yv[q + 1] - yv[q]) * (dv[q + 1] + dv[q]) * 0.5f;
        }
    }

    // block reduce: wave64 shuffle (double for cross-thread accumulation safety)
    double smd = (double)sm, trd = (double)tr;
    for (int off = 32; off > 0; off >>= 1) {
        smd += __shfl_down(smd, off, 64);
        trd += __shfl_down(trd, off, 64);
    }
    __shared__ double s_sm[4], s_tr[4];
    const int wave = tid >> 6, lane = tid & 63;
    if (lane == 0) { s_sm[wave] = smd; s_tr[wave] = trd; }
    __syncthreads();
    if (tid == 0) {
        double2 r;
        r.x = s_sm[0] + s_sm[1] + s_sm[2] + s_sm[3];
        r.y = s_tr[0] + s_tr[1] + s_tr[2] + s_tr[3];
        ws2[b * NSPLIT + s] = r;     // always written -> no poison hazard
    }
}

// Kernel 2: one thread per row -- combine partials (fixed order), epilogue + out MLP.
__global__ __launch_bounds__(256) void frac_final_kernel(
    const float* __restrict__ y_plus,
    const int*   __restrict__ iidx,
    const float* __restrict__ DU,
    const float* __restrict__ Y,
    const float* __restrict__ aw1, const float* __restrict__ ab1,
    const float* __restrict__ aw2, const float* __restrict__ ab2,
    const float* __restrict__ w1,  const float* __restrict__ b1,
    const float* __restrict__ w2,  const float* __restrict__ b2,
    const double2* __restrict__ ws2,
    float* __restrict__ out)
{
    const int b = blockIdx.x * 256 + threadIdx.x;
    if (b >= BB) return;
    const int n = iidx[b];
    const float a = alpha_of(y_plus[b], aw1, ab1, aw2, ab2);
    const float t = 1.f - a;

    double sm = 0.0, tr = 0.0;
    #pragma unroll
    for (int s = 0; s < NSPLIT; ++s) {
        double2 r = ws2[b * NSPLIT + s];
        sm += r.x; tr += r.y;
    }

    const float* yr = Y  + (size_t)b * NN;
    const float* dr = DU + (size_t)b * NN;

    float dres;
    if (a == 0.f) {
        dres = (float)tr;
    } else if (a == 1.f) {
        dres = dr[n];
    } else if (n == 0) {
        dres = 0.f;
    } else {
        float last = powf(yr[n] - yr[n - 1], t) * dr[n - 1];  // once per row: exact powf
        float fac  = expf(-lgammaf(2.f - a));
        dres = fac * ((float)sm + last);
    }
    float o = b2[0];
    #pragma unroll
    for (int h = 0; h < HH; ++h)
        o += fmaxf(fmaf(dres, w1[h], b1[h]), 0.f) * w2[h];
    out[b] = o;
}

extern "C" void kernel_launch(void* const* d_in, const int* in_sizes, int n_in,
                              void* d_out, int out_size, void* d_ws, size_t ws_size,
                              hipStream_t stream) {
    const float* y_plus = (const float*)d_in[0];
    const int*   iidx   = (const int*)  d_in[1];
    const float* DU     = (const float*)d_in[2];
    const float* Y      = (const float*)d_in[3];
    const float* aw1    = (const float*)d_in[4];
    const float* ab1    = (const float*)d_in[5];
    const float* aw2    = (const float*)d_in[6];
    const float* ab2    = (const float*)d_in[7];
    const float* w1     = (const float*)d_in[8];
    const float* b1     = (const float*)d_in[9];
    const float* w2     = (const float*)d_in[10];
    const float* b2     = (const float*)d_in[11];
    float* out = (float*)d_out;
    double2* ws2 = (double2*)d_ws;

    dim3 grid1(BB, NSPLIT);
    frac_partial_kernel<<<grid1, 256, 0, stream>>>(y_plus, iidx, DU, Y,
                                                   aw1, ab1, aw2, ab2, ws2);
    frac_final_kernel<<<(BB + 255) / 256, 256, 0, stream>>>(y_plus, iidx, DU, Y,
                                                            aw1, ab1, aw2, ab2,
                                                            w1, b1, w2, b2, ws2, out);
}